// Round 3
// baseline (318.442 us; speedup 1.0000x reference)
//
#include <hip/hip_runtime.h>

// ---------------------------------------------------------------------------
// LiteMLA: B=4, N=4096, C=1024, D=32, h=32 heads.
//   qkv = x @ W_qkv^T            (16384 x 3072, K=1024)   [relu on q,k cols]
//   per (b,h): vk[d,e] = sum_n Vpad[d,n]*reluK[e,n]   (33x32, reduce N=4096)
//              y[d,n]  = (sum_e vk[d,e]*reluQ[e,n]) / (sum_e vk[32,e]*reluQ[e,n] + eps)
//   out = y @ W_proj^T + b_proj  (16384 x 1024, K=1024)
//
// GEMM: 256x256 tile, BK=64, **4 waves of 128x128 each** (LDS-BW theory:
// per-wave tile (W_M+W_N)/(W_M*W_N) sets LDS read demand; 128x128 halves it
// vs 128x64 -> ceiling 61% -> 82% MfmaUtil). 8 LDS regions of 16 KiB
// ([2buf][2khalf] per operand), 4 phases/K-tile:
//   P1: stage B_k1(g+1)->c^1 ; read af0 + B0(ni0-3) ; 32 MFMA (kk0)
//   P2: stage A_k0(g+2)->c   ; read B0(ni4-7) + af1 ; 32 MFMA (kk0) ; vmcnt(16)
//   P3: stage B_k0(g+2)->c   ; read B1(ni0-3)       ; 32 MFMA (kk1)
//   P4: stage A_k1(g+2)->c   ; read B1(ni4-7)       ; 32 MFMA (kk1) ; vmcnt(16)
// One barrier per phase. Region-drain-before-stage invariants:
//   A_k0 reads end P1, staged P2; B_k0 reads end P2, staged P3; A_k1 reads
//   end P2 (prefetch), staged P4; B_k1 reads end P4, staged next-iter P1.
// vmcnt(16)@P2 retires stage g-1.P1 (B_k1(g)) before g.P3 reads it;
// vmcnt(16)@P4 retires all of tile g+1 before iter g+1. Never drains to 0.
// LDS layout per region: [128 row-pairs][64]: elem(row,k) at
// (row>>1)*64 + (row&1)*32 + ((k>>3)^((row>>1)&3))*8 + (k&7)  -> bank-balanced
// b128 reads (8 accesses/bank = minimum). DMA dest linear; global source
// pre-swizzled per chunk. Accumulation order per element unchanged (g asc,
// kk asc) -> bit-identical numerics vs verified kernel.
// ---------------------------------------------------------------------------

using us8   = __attribute__((ext_vector_type(8))) unsigned short;
using us4   = __attribute__((ext_vector_type(4))) unsigned short;
using s8v   = __attribute__((ext_vector_type(8))) short;
using f32x4 = __attribute__((ext_vector_type(4))) float;

__device__ __forceinline__ unsigned short f2bf(float f) {
    union { float f; unsigned int u; } c; c.f = f;
    unsigned int r = c.u + 0x7fffu + ((c.u >> 16) & 1u);   // RTN-even
    return (unsigned short)(r >> 16);
}
__device__ __forceinline__ float bf2f(unsigned short u) {
    union { unsigned int u; float f; } c; c.u = ((unsigned int)u) << 16;
    return c.f;
}

// async global->LDS, 16B per lane; LDS dest = wave-uniform base + lane*16
__device__ __forceinline__ void async16(const unsigned short* g, unsigned short* l) {
    __builtin_amdgcn_global_load_lds(
        (const __attribute__((address_space(1))) unsigned int*)g,
        (__attribute__((address_space(3))) unsigned int*)l, 16, 0, 0);
}

// ------------------ fused fp32->bf16 converts + vkws zero ------------------
__global__ __launch_bounds__(256)
void prep(const float* __restrict__ x, const float* __restrict__ wq,
          const float* __restrict__ wp, unsigned short* __restrict__ xb,
          unsigned short* __restrict__ wqb, unsigned short* __restrict__ wpb,
          float* __restrict__ vkws) {
    const int NX = 16777216 / 8, NQ = 3145728 / 8, NP = 1048576 / 8, NZ = 135168 / 8;
    int gid = blockIdx.x * 256 + threadIdx.x;
    const float* in; unsigned short* out; int i;
    if (gid < NX)                    { in = x;  out = xb;  i = gid * 8; }
    else if (gid < NX + NQ)          { in = wq; out = wqb; i = (gid - NX) * 8; }
    else if (gid < NX + NQ + NP)     { in = wp; out = wpb; i = (gid - NX - NQ) * 8; }
    else if (gid < NX + NQ + NP + NZ) {
        int z = (gid - NX - NQ - NP) * 8;
        f32x4 zero = {};
        *(f32x4*)(vkws + z) = zero; *(f32x4*)(vkws + z + 4) = zero;
        return;
    } else return;
    float4 a = *(const float4*)(in + i);
    float4 b = *(const float4*)(in + i + 4);
    us8 o;
    o[0] = f2bf(a.x); o[1] = f2bf(a.y); o[2] = f2bf(a.z); o[3] = f2bf(a.w);
    o[4] = f2bf(b.x); o[5] = f2bf(b.y); o[6] = f2bf(b.z); o[7] = f2bf(b.w);
    *(us8*)(out + i) = o;
}

// ----------------------- 256x256 fat-wave GEMM core ------------------------
constexpr int RSZ = 8192;                 // elements per 16 KiB region

#define FENCE() asm volatile("" ::: "memory")
#define BARX()  do { FENCE(); __builtin_amdgcn_s_barrier(); FENCE(); } while (0)
#define LGKM0() asm volatile("s_waitcnt lgkmcnt(0)" ::: "memory")

// 32 MFMA: all 8 mi x 4 ni (NB..NB+3) against one k-half A set
#define MFMA_P(AF, NB)                                                       \
  do {                                                                       \
    __builtin_amdgcn_s_setprio(1);                                           \
    _Pragma("unroll")                                                        \
    for (int mi_ = 0; mi_ < 8; ++mi_)                                        \
      _Pragma("unroll")                                                      \
      for (int nj_ = 0; nj_ < 4; ++nj_)                                      \
        acc[mi_][(NB) + nj_] = __builtin_amdgcn_mfma_f32_16x16x32_bf16(      \
            AF[mi_], bfr[nj_], acc[mi_][(NB) + nj_], 0, 0, 0);               \
    __builtin_amdgcn_s_setprio(0);                                           \
  } while (0)

// stage one 256x32 region (16 KiB): 4 async16 per thread, linear LDS dest,
// pre-swizzled global source (goff decoded once per thread).
__device__ __forceinline__
void stage_reg(const unsigned short* __restrict__ G, int rowBase, int kcol,
               unsigned short* region, const int* goff, int wv) {
#pragma unroll
    for (int j = 0; j < 4; ++j)
        async16(G + (size_t)rowBase * 1024 + kcol + goff[j],
                region + wv * 2048 + j * 512);
}

// MODE 0: cols<1024 -> Q token-major bf16 (relu); cols>=1024 -> kvT.
// MODE 1: fp32 + bias.
template <int MODE>
__device__ __forceinline__
void gemm_core256(const unsigned short* __restrict__ A,
                  const unsigned short* __restrict__ Bt,
                  unsigned short* __restrict__ Cq,
                  unsigned short* __restrict__ kvT,
                  float* __restrict__ Cf, const float* __restrict__ bias,
                  int N, int tM, int tN, unsigned short* lds) {
    unsigned short* As = lds;                 // [2buf][2khalf] regions
    unsigned short* Bs = lds + 4 * RSZ;

    const int t    = threadIdx.x;
    const int lane = t & 63;
    const int wv   = t >> 6;                  // 4 waves
    const int wr   = wv >> 1;                 // 0..1 : 128-row slab
    const int wc   = wv & 1;                  // 0..1 : 128-col slab
    const int mrow = lane & 15;
    const int kq   = lane >> 4;               // 0..3
    const int slot = kq ^ ((mrow >> 1) & 3);  // bank-spread XOR

    // ds_read element offsets within a region (frag i at +i*512)
    const int a_off = (wr * 64 + (mrow >> 1)) * 64 + (mrow & 1) * 32 + slot * 8;
    const int b_off = (wc * 64 + (mrow >> 1)) * 64 + (mrow & 1) * 32 + slot * 8;

    // staging decode: chunk c = wv*256 + j*64 + lane -> logical (row, kq)
    int goff[4];
#pragma unroll
    for (int j = 0; j < 4; ++j) {
        int c   = wv * 256 + j * 64 + lane;
        int row = ((c >> 3) << 1) + ((c >> 2) & 1);
        int kqq = (c & 3) ^ ((c >> 3) & 3);
        goff[j] = row * 1024 + kqq * 8;
    }

    f32x4 acc[8][8] = {};
    s8v af0[8], af1[8], bfr[4];

    constexpr int NT = 16;                    // K = 1024 = 16 x 64

    // prologue: tile0 all 4 regions -> buf0; tile1 A_k0,B_k0,A_k1 -> buf1
    stage_reg(A,  tM, 0,       As + 0 * RSZ, goff, wv);
    stage_reg(A,  tM, 32,      As + 1 * RSZ, goff, wv);
    stage_reg(Bt, tN, 0,       Bs + 0 * RSZ, goff, wv);
    stage_reg(Bt, tN, 32,      Bs + 1 * RSZ, goff, wv);
    stage_reg(A,  tM, 64,      As + 2 * RSZ, goff, wv);
    stage_reg(Bt, tN, 64,      Bs + 2 * RSZ, goff, wv);
    stage_reg(A,  tM, 96,      As + 3 * RSZ, goff, wv);
    asm volatile("s_waitcnt vmcnt(12)" ::: "memory");   // tile0 landed
    BARX();

    for (int g = 0; g < NT; ++g) {
        const int c = g & 1;
        const unsigned short* A0 = As + (c * 2 + 0) * RSZ;
        const unsigned short* A1 = As + (c * 2 + 1) * RSZ;
        const unsigned short* B0 = Bs + (c * 2 + 0) * RSZ;
        const unsigned short* B1 = Bs + (c * 2 + 1) * RSZ;
        const int kt1 = (g + 1 < NT ? g + 1 : NT - 1) * 64;
        const int kt2 = (g + 2 < NT ? g + 2 : NT - 1) * 64;

        // ---- P1: stage B_k1(g+1)->c^1 ; read af0 + B0 ni0-3 ; MFMA kk0 ----
        stage_reg(Bt, tN, kt1 + 32, Bs + ((c ^ 1) * 2 + 1) * RSZ, goff, wv);
#pragma unroll
        for (int mi = 0; mi < 8; ++mi)
            af0[mi] = *(const s8v*)&A0[a_off + mi * 512];
#pragma unroll
        for (int nj = 0; nj < 4; ++nj)
            bfr[nj] = *(const s8v*)&B0[b_off + nj * 512];
        MFMA_P(af0, 0);
        LGKM0();
        BARX();

        // ---- P2: stage A_k0(g+2)->c ; read B0 ni4-7 + prefetch af1 --------
        stage_reg(A, tM, kt2, As + (c * 2 + 0) * RSZ, goff, wv);
#pragma unroll
        for (int nj = 0; nj < 4; ++nj)
            bfr[nj] = *(const s8v*)&B0[b_off + (4 + nj) * 512];
#pragma unroll
        for (int mi = 0; mi < 8; ++mi)
            af1[mi] = *(const s8v*)&A1[a_off + mi * 512];
        MFMA_P(af0, 4);
        LGKM0();
        asm volatile("s_waitcnt vmcnt(16)" ::: "memory");  // retire g-1.P1
        BARX();

        // ---- P3: stage B_k0(g+2)->c ; read B1 ni0-3 ; MFMA kk1 ------------
        stage_reg(Bt, tN, kt2, Bs + (c * 2 + 0) * RSZ, goff, wv);
#pragma unroll
        for (int nj = 0; nj < 4; ++nj)
            bfr[nj] = *(const s8v*)&B1[b_off + nj * 512];
        MFMA_P(af1, 0);
        LGKM0();
        BARX();

        // ---- P4: stage A_k1(g+2)->c ; read B1 ni4-7 ; MFMA kk1 ------------
        stage_reg(A, tM, kt2 + 32, As + (c * 2 + 1) * RSZ, goff, wv);
#pragma unroll
        for (int nj = 0; nj < 4; ++nj)
            bfr[nj] = *(const s8v*)&B1[b_off + (4 + nj) * 512];
        MFMA_P(af1, 4);
        LGKM0();
        asm volatile("s_waitcnt vmcnt(16)" ::: "memory");  // tile g+1 landed
        BARX();
    }

    // ----------------------------- epilogue --------------------------------
    const int crow0 = kq * 4;
    if (MODE == 0) {
        if (tN >= 1024) {
            const int b2  = tM >> 12;
            const int nb0 = (tM & 4095) + wr * 128;
#pragma unroll
            for (int mi = 0; mi < 8; ++mi) {
                const int nbase = nb0 + mi * 16 + crow0;
#pragma unroll
                for (int ni = 0; ni < 8; ++ni) {
                    const int col = tN + wc * 128 + ni * 16 + mrow;
                    f32x4 v = acc[mi][ni];
                    if (col < 2048) {
                        v[0] = fmaxf(v[0], 0.f); v[1] = fmaxf(v[1], 0.f);
                        v[2] = fmaxf(v[2], 0.f); v[3] = fmaxf(v[3], 0.f);
                    }
                    us4 o;
                    o[0] = f2bf(v[0]); o[1] = f2bf(v[1]);
                    o[2] = f2bf(v[2]); o[3] = f2bf(v[3]);
                    *(us4*)&kvT[((size_t)b2 * 2048 + (col - 1024)) * 4096 + nbase] = o;
                }
            }
        } else {
#pragma unroll
            for (int mi = 0; mi < 8; ++mi)
#pragma unroll
                for (int ni = 0; ni < 8; ++ni) {
                    const int row = tM + wr * 128 + mi * 16 + crow0;
                    const int col = tN + wc * 128 + ni * 16 + mrow;
#pragma unroll
                    for (int r2 = 0; r2 < 4; ++r2)
                        Cq[(size_t)(row + r2) * 1024 + col] =
                            f2bf(fmaxf(acc[mi][ni][r2], 0.f));
                }
        }
    } else {
#pragma unroll
        for (int mi = 0; mi < 8; ++mi)
#pragma unroll
            for (int ni = 0; ni < 8; ++ni) {
                const int row = tM + wr * 128 + mi * 16 + crow0;
                const int col = tN + wc * 128 + ni * 16 + mrow;
#pragma unroll
                for (int r2 = 0; r2 < 4; ++r2)
                    Cf[(size_t)(row + r2) * N + col] = acc[mi][ni][r2] + bias[col];
            }
    }
    // drain LDS-DMA before wave exit (LDS may be re-allocated to next block)
    asm volatile("s_waitcnt vmcnt(0)" ::: "memory");
}

// XCD-aware tile map: xcd = blk&7 owns an 8-M-tile stripe; N swept in panels
// of 4 (B-panel 2 MB stays L2-hot), tN fastest within panel.
__device__ __forceinline__ void xcd_map256(int blk, int MT, int& tM, int& tN) {
    const int xcd = blk & 7;
    const int i   = blk >> 3;
    const int MTx = MT >> 3;             // M-tiles per XCD (8)
    const int ppan = MTx * 4;            // blocks per 4-wide panel per XCD
    const int p   = i / ppan;
    const int i2  = i % ppan;
    tM = (xcd * MTx + (i2 >> 2)) * 256;
    tN = (p * 4 + (i2 & 3)) * 256;
}

__global__ __launch_bounds__(256, 1)
void gemm_qkv(const unsigned short* __restrict__ A,
              const unsigned short* __restrict__ Bt,
              unsigned short* __restrict__ Cq, unsigned short* __restrict__ kvT,
              int M, int N) {
    extern __shared__ unsigned short lds[];
    int tM, tN;
    xcd_map256(blockIdx.x, M >> 8, tM, tN);
    gemm_core256<0>(A, Bt, Cq, kvT, nullptr, nullptr, N, tM, tN, lds);
}

__global__ __launch_bounds__(256, 1)
void gemm_proj(const unsigned short* __restrict__ A,
               const unsigned short* __restrict__ Bt,
               float* __restrict__ C, const float* __restrict__ bias,
               int M, int N) {
    extern __shared__ unsigned short lds[];
    int tM, tN;
    xcd_map256(blockIdx.x, M >> 8, tM, tN);
    gemm_core256<1>(A, Bt, nullptr, nullptr, C, bias, N, tM, tN, lds);
}

// ---------------- vk = Vpad @ reluK^T via MFMA over kvT --------------------
__global__ __launch_bounds__(256)
void lite_vk(const unsigned short* __restrict__ kvT, float* __restrict__ vkws) {
    const int bh = blockIdx.x, ck = blockIdx.y;
    const int b = bh >> 5, h = bh & 31;
    const int S = 136;
    __shared__ unsigned short Ks[32 * S];
    __shared__ unsigned short Vs[32 * S];
    __shared__ float Rs[4][1088];
    const int t = threadIdx.x, lane = t & 63, wv = t >> 6;
    const unsigned short* Kp = kvT + ((size_t)b * 2048 + h * 32) * 4096 + ck * 512;
    const unsigned short* Vp = kvT + ((size_t)b * 2048 + 1024 + h * 32) * 4096 + ck * 512;
    const int sr = t >> 3, ss = (t & 7) * 16;
    f32x4 acc00 = {}, acc01 = {}, acc10 = {}, acc11 = {}, accO0 = {}, accO1 = {};
    s8v ones;
#pragma unroll
    for (int j = 0; j < 8; ++j) ones[j] = (short)0x3F80;
    const int mrow = lane & 15, kq = (lane >> 4) * 8;

    for (int tile = 0; tile < 4; ++tile) {
        int go = tile * 128 + ss;
        us8 k0v = *(const us8*)(Kp + (size_t)sr * 4096 + go);
        us8 k1v = *(const us8*)(Kp + (size_t)sr * 4096 + go + 8);
        us8 v0v = *(const us8*)(Vp + (size_t)sr * 4096 + go);
        us8 v1v = *(const us8*)(Vp + (size_t)sr * 4096 + go + 8);
        __syncthreads();
        *(us8*)&Ks[sr * S + ss]     = k0v;
        *(us8*)&Ks[sr * S + ss + 8] = k1v;
        *(us8*)&Vs[sr * S + ss]     = v0v;
        *(us8*)&Vs[sr * S + ss + 8] = v1v;
        __syncthreads();
        int ko = wv * 32 + kq;
        s8v a0 = *(const s8v*)&Vs[(mrow)      * S + ko];
        s8v a1 = *(const s8v*)&Vs[(16 + mrow) * S + ko];
        s8v b0 = *(const s8v*)&Ks[(mrow)      * S + ko];
        s8v b1 = *(const s8v*)&Ks[(16 + mrow) * S + ko];
        acc00 = __builtin_amdgcn_mfma_f32_16x16x32_bf16(a0, b0, acc00, 0, 0, 0);
        acc01 = __builtin_amdgcn_mfma_f32_16x16x32_bf16(a0, b1, acc01, 0, 0, 0);
        acc10 = __builtin_amdgcn_mfma_f32_16x16x32_bf16(a1, b0, acc10, 0, 0, 0);
        acc11 = __builtin_amdgcn_mfma_f32_16x16x32_bf16(a1, b1, acc11, 0, 0, 0);
        accO0 = __builtin_amdgcn_mfma_f32_16x16x32_bf16(ones, b0, accO0, 0, 0, 0);
        accO1 = __builtin_amdgcn_mfma_f32_16x16x32_bf16(ones, b1, accO1, 0, 0, 0);
    }

    const int ccol = lane & 15, crow = (lane >> 4) * 4;
    float* R = Rs[wv];
#pragma unroll
    for (int r2 = 0; r2 < 4; ++r2) {
        R[(crow + r2) * 32 + ccol]           = acc00[r2];
        R[(crow + r2) * 32 + 16 + ccol]      = acc01[r2];
        R[(16 + crow + r2) * 32 + ccol]      = acc10[r2];
        R[(16 + crow + r2) * 32 + 16 + ccol] = acc11[r2];
    }
    if ((lane >> 4) == 0) {
        R[1024 + ccol]      = accO0[0];
        R[1024 + 16 + ccol] = accO1[0];
    }
    __syncthreads();
    float* vkb = vkws + bh * (33 * 32);
    for (int i = t; i < 1056; i += 256) {
        float s = Rs[0][i] + Rs[1][i] + Rs[2][i] + Rs[3][i];
        atomicAdd(&vkb[i], s);
    }
}

// --------------- y = (vk @ reluQ) / pad-row, MFMA K=32 ---------------------
__global__ __launch_bounds__(256)
void lite_apply(const unsigned short* __restrict__ qb,
                const float* __restrict__ vkws,
                unsigned short* __restrict__ yb) {
    const int bh = blockIdx.x, nb = blockIdx.y;
    const int b = bh >> 5, h = bh & 31;
    __shared__ unsigned short vkh[48 * 32];
    __shared__ unsigned short vkl[48 * 32];
    const int t = threadIdx.x;
    for (int i = t; i < 48 * 32; i += 256) {
        float v = (i < 33 * 32) ? vkws[bh * (33 * 32) + i] : 0.f;
        unsigned short hi = f2bf(v);
        vkh[i] = hi;
        vkl[i] = f2bf(v - bf2f(hi));
    }
    __syncthreads();

    const int lane = t & 63, wv = t >> 6;
    const int col = lane & 15, quad = lane >> 4;
    s8v b0h = *(const s8v*)&vkh[(col)      * 32 + quad * 8];
    s8v b0l = *(const s8v*)&vkl[(col)      * 32 + quad * 8];
    s8v b1h = *(const s8v*)&vkh[(16 + col) * 32 + quad * 8];
    s8v b1l = *(const s8v*)&vkl[(16 + col) * 32 + quad * 8];
    s8v b2h = *(const s8v*)&vkh[(32 + col) * 32 + quad * 8];
    s8v b2l = *(const s8v*)&vkl[(32 + col) * 32 + quad * 8];

    const int ntile = nb * 256 + wv * 64;
#pragma unroll
    for (int mi = 0; mi < 4; ++mi) {
        int tok = ntile + mi * 16 + col;
        const unsigned short* qp =
            qb + (size_t)(b * 4096 + tok) * 1024 + h * 32 + quad * 8;
        s8v a = *(const s8v*)qp;
        f32x4 n0 = {}, n1 = {}, dd = {};
        n0 = __builtin_amdgcn_mfma_f32_16x16x32_bf16(b0h, a, n0, 0, 0, 0);
        n0 = __builtin_amdgcn_mfma_f32_16x16x32_bf16(b0l, a, n0, 0, 0, 0);
        n1 = __builtin_amdgcn_mfma_f32_16x16x32_bf16(b1h, a, n1, 0, 0, 0);
        n1 = __builtin_amdgcn_mfma_f32_16x16x32_bf16(b1l, a, n1, 0, 0, 0);
        dd = __builtin_amdgcn_mfma_f32_16x16x32_bf16(b2h, a, dd, 0, 0, 0);
        dd = __builtin_amdgcn_mfma_f32_16x16x32_bf16(b2l, a, dd, 0, 0, 0);
        float den  = __shfl(dd[0], col, 64);
        float rinv = 1.f / (den + 1e-15f);
        us4 o0, o1;
#pragma unroll
        for (int r = 0; r < 4; ++r) {
            o0[r] = f2bf(n0[r] * rinv);
            o1[r] = f2bf(n1[r] * rinv);
        }
        size_t o = (size_t)(b * 4096 + tok) * 1024 + h * 32;
        *(us4*)&yb[o + quad * 4]      = o0;
        *(us4*)&yb[o + 16 + quad * 4] = o1;
    }
}

// ---------------------------------------------------------------------------
extern "C" void kernel_launch(void* const* d_in, const int* in_sizes, int n_in,
                              void* d_out, int out_size, void* d_ws, size_t ws_size,
                              hipStream_t stream) {
    const float* x     = (const float*)d_in[0];   // (4,4096,1024)
    const float* Wqkv  = (const float*)d_in[1];   // (3072,1024)
    const float* Wproj = (const float*)d_in[2];   // (1024,1024)
    const float* bproj = (const float*)d_in[3];   // (1024,)
    float* out = (float*)d_out;                   // (4,4096,1024) fp32

    const int M = 16384, Cdim = 1024, O1 = 3072;

    unsigned short* xb     = (unsigned short*)d_ws;
    unsigned short* wqkvb  = xb + (size_t)M * Cdim;
    unsigned short* wprojb = wqkvb + (size_t)O1 * Cdim;
    unsigned short* qb     = wprojb + (size_t)Cdim * Cdim;        // Q token-major
    unsigned short* kvT    = qb + (size_t)M * Cdim;               // [4][2048][4096]
    unsigned short* ybuf   = kvT + (size_t)4 * 2048 * 4096;
    float* vkws            = (float*)(ybuf + (size_t)M * Cdim);
    // ws use: ~176 MB

    static int attr_done = 0;
    if (!attr_done) {
        hipFuncSetAttribute((const void*)gemm_qkv,
                            hipFuncAttributeMaxDynamicSharedMemorySize, 131072);
        hipFuncSetAttribute((const void*)gemm_proj,
                            hipFuncAttributeMaxDynamicSharedMemorySize, 131072);
        attr_done = 1;
    }

    const int PREP_GROUPS = (16777216 + 3145728 + 1048576 + 135168) / 8;
    prep<<<(PREP_GROUPS + 255) / 256, 256, 0, stream>>>(
        x, Wqkv, Wproj, xb, wqkvb, wprojb, vkws);

    gemm_qkv<<<(M / 256) * (O1 / 256), 256, 131072, stream>>>(
        xb, wqkvb, qb, kvT, M, O1);

    lite_vk<<<dim3(128, 8), 256, 0, stream>>>(kvT, vkws);
    lite_apply<<<dim3(128, 16), 256, 0, stream>>>(qb, vkws, ybuf);

    gemm_proj<<<(M / 256) * (Cdim / 256), 256, 131072, stream>>>(
        ybuf, wprojb, out, bproj, M, Cdim);
}

// Round 4
// 300.134 us; speedup vs baseline: 1.0610x; 1.0610x over previous
//
#include <hip/hip_runtime.h>

// ---------------------------------------------------------------------------
// LiteMLA: B=4, N=4096, C=1024, D=32, h=32 heads.
//   qkv = x @ W_qkv^T            (16384 x 3072, K=1024)   [relu on q,k cols]
//   per (b,h): vk[d,e] = sum_n Vpad[d,n]*reluK[e,n]   (33x32, reduce N=4096)
//              y[d,n]  = (sum_e vk[d,e]*reluQ[e,n]) / (sum_e vk[32,e]*reluQ[e,n] + eps)
//   out = y @ W_proj^T + b_proj  (16384 x 1024, K=1024)
//
// GEMM: 256x256 tile, BK=64, 8 waves (128x64 per wave), 128 KiB LDS,
// 4 phases/K-tile with frag reads PIPELINED ONE PHASE AHEAD (reads for
// phase p+1 issue during phase p -> LDS pipe overlaps MFMA pipe; this was
// the serialization pinning R1-R3 at ~40% MfmaUtil):
//   Φ1: read bf23(g)            ; MFMA(afP, bf01) q(0,0) ; bar
//   Φ2: stage B0(g+2)->B[c][0]  ; read afQ=M1(g) ; MFMA(afP, bf23) q(0,2) ; bar
//   Φ3: stage B1(g+2)->B[c][1]  ;                 MFMA(afQ, bf01) q(4,0) ; bar
//   Φ4: vmcnt(4) ; read afP=M0(g+1)+bf01(g+1) from buf c^1 ;
//       stage A0,A1(g+2)->A[c]  ; MFMA(afQ, bf23) q(4,2) ; bar
// Region-overwrite safety: every region's reads are consumed (compiler
// auto-lgkmcnt before MFMA) >=1 barrier before the stage into it.
// vmcnt(4)@Φ4 retires ALL of tile g+1 (12 outstanding -> keep 4 newest =
// B0,B1(g+2)); never drains to 0 in-loop. Prologue stages tiles 0+1 (16
// loads), vmcnt(8) -> identical steady state. Frag double-buffers:
// afP/afQ[4][2] + bf01/bf23[2][2] = 96 VGPR; acc[8][4] in AGPR (128).
// Accumulation order per element unchanged -> bit-identical numerics.
// LDS slot swizzle (kk*4+kq)^(lane&7) on ds_read addr + pre-swizzled global
// source (linear DMA dest) -- unchanged from verified kernel, conflicts 0.
// ---------------------------------------------------------------------------

using us8   = __attribute__((ext_vector_type(8))) unsigned short;
using us4   = __attribute__((ext_vector_type(4))) unsigned short;
using s8v   = __attribute__((ext_vector_type(8))) short;
using f32x4 = __attribute__((ext_vector_type(4))) float;

__device__ __forceinline__ unsigned short f2bf(float f) {
    union { float f; unsigned int u; } c; c.f = f;
    unsigned int r = c.u + 0x7fffu + ((c.u >> 16) & 1u);   // RTN-even
    return (unsigned short)(r >> 16);
}
__device__ __forceinline__ float bf2f(unsigned short u) {
    union { unsigned int u; float f; } c; c.u = ((unsigned int)u) << 16;
    return c.f;
}

// async global->LDS, 16B per lane; LDS dest = wave-uniform base + lane*16
__device__ __forceinline__ void async16(const unsigned short* g, unsigned short* l) {
    __builtin_amdgcn_global_load_lds(
        (const __attribute__((address_space(1))) unsigned int*)g,
        (__attribute__((address_space(3))) unsigned int*)l, 16, 0, 0);
}

// ------------------ fused fp32->bf16 converts + vkws zero ------------------
__global__ __launch_bounds__(256)
void prep(const float* __restrict__ x, const float* __restrict__ wq,
          const float* __restrict__ wp, unsigned short* __restrict__ xb,
          unsigned short* __restrict__ wqb, unsigned short* __restrict__ wpb,
          float* __restrict__ vkws) {
    const int NX = 16777216 / 8, NQ = 3145728 / 8, NP = 1048576 / 8, NZ = 135168 / 8;
    int gid = blockIdx.x * 256 + threadIdx.x;
    const float* in; unsigned short* out; int i;
    if (gid < NX)                    { in = x;  out = xb;  i = gid * 8; }
    else if (gid < NX + NQ)          { in = wq; out = wqb; i = (gid - NX) * 8; }
    else if (gid < NX + NQ + NP)     { in = wp; out = wpb; i = (gid - NX - NQ) * 8; }
    else if (gid < NX + NQ + NP + NZ) {
        int z = (gid - NX - NQ - NP) * 8;
        f32x4 zero = {};
        *(f32x4*)(vkws + z) = zero; *(f32x4*)(vkws + z + 4) = zero;
        return;
    } else return;
    float4 a = *(const float4*)(in + i);
    float4 b = *(const float4*)(in + i + 4);
    us8 o;
    o[0] = f2bf(a.x); o[1] = f2bf(a.y); o[2] = f2bf(a.z); o[3] = f2bf(a.w);
    o[4] = f2bf(b.x); o[5] = f2bf(b.y); o[6] = f2bf(b.z); o[7] = f2bf(b.w);
    *(us8*)(out + i) = o;
}

// ----------------------- 256x256 pipelined GEMM core -----------------------
constexpr int HSZ = 128 * 64;            // elements per half-region (16 KiB)

#define FENCE() asm volatile("" ::: "memory")
#define BARX()  do { FENCE(); __builtin_amdgcn_s_barrier(); FENCE(); } while (0)

#define MFMA_QUAD2(AF, BF, MB, NB)                                           \
  do {                                                                       \
    __builtin_amdgcn_s_setprio(1);                                           \
    _Pragma("unroll")                                                        \
    for (int mi_ = 0; mi_ < 4; ++mi_)                                        \
      _Pragma("unroll")                                                      \
      for (int ni_ = 0; ni_ < 2; ++ni_)                                      \
        _Pragma("unroll")                                                    \
        for (int kk_ = 0; kk_ < 2; ++kk_)                                    \
          acc[(MB) + mi_][(NB) + ni_] =                                      \
              __builtin_amdgcn_mfma_f32_16x16x32_bf16(                       \
                  AF[mi_][kk_], BF[ni_][kk_],                                \
                  acc[(MB) + mi_][(NB) + ni_], 0, 0, 0);                     \
    __builtin_amdgcn_s_setprio(0);                                           \
  } while (0)

// stage one 128x64 half-tile: 2 async16/thread off the per-thread swizzled
// global base; roff = 0 (rows 0-127) or 131072 (rows 128-255), kc in elems.
__device__ __forceinline__
void stage2(const unsigned short* gl, int kc, int roff,
            unsigned short* region, int wv) {
    async16(gl + kc + roff,         region + wv * 512);
    async16(gl + kc + roff + 65536, region + 4096 + wv * 512);
}

// MODE 0: cols<1024 -> Q token-major bf16 (relu); cols>=1024 -> kvT.
// MODE 1: fp32 + bias.
template <int MODE>
__device__ __forceinline__
void gemm_core256(const unsigned short* __restrict__ A,
                  const unsigned short* __restrict__ Bt,
                  unsigned short* __restrict__ Cq,
                  unsigned short* __restrict__ kvT,
                  float* __restrict__ Cf, const float* __restrict__ bias,
                  int N, int tM, int tN, unsigned short* lds) {
    unsigned short* As = lds;                 // [2buf][2 M-half] regions
    unsigned short* Bs = lds + 4 * HSZ;       // [2buf][2 N-half] regions

    const int t    = threadIdx.x;
    const int lane = t & 63;
    const int wv   = t >> 6;
    const int wr   = wv >> 2;                 // 0..1 : A 128-row slab
    const int wc   = wv & 3;                  // 0..3 : 32-row group per B half
    const int mrow = lane & 15;
    const int kq   = lane >> 4;               // 0..3
    const int m7   = lane & 7;

    // staging thread map: row0 = t>>3 (0..63), swizzled source element
    const int row0 = t >> 3;
    const int esw  = ((t & 7) ^ (row0 & 7)) * 8;
    const unsigned short* Aglane = A  + (size_t)(tM + row0) * 1024 + esw;
    const unsigned short* Bglane = Bt + (size_t)(tN + row0) * 1024 + esw;

    // swizzled k-slot element offsets for ds_read (kk=0/1)
    const int ks0 = ((0 * 4 + kq) ^ m7) * 8;
    const int ks1 = ((1 * 4 + kq) ^ m7) * 8;
    const int browB = wc * 32;                // row group inside each B half

    f32x4 acc[8][4] = {};
    s8v afP[4][2], afQ[4][2], bf01[2][2], bf23[2][2];

    constexpr int NT = 16;                    // K = 1024 = 16 x 64

    // prologue: tile0 -> buf0 (4 regions), tile1 -> buf1 (4 regions)
    stage2(Aglane, 0,  0,      As + 0 * HSZ, wv);   // A0(0)
    stage2(Aglane, 0,  131072, As + 1 * HSZ, wv);   // A1(0)
    stage2(Bglane, 0,  0,      Bs + 0 * HSZ, wv);   // B0(0)
    stage2(Bglane, 0,  131072, Bs + 1 * HSZ, wv);   // B1(0)
    stage2(Aglane, 64, 0,      As + 2 * HSZ, wv);   // A0(1)
    stage2(Aglane, 64, 131072, As + 3 * HSZ, wv);   // A1(1)
    stage2(Bglane, 64, 0,      Bs + 2 * HSZ, wv);   // B0(1)
    stage2(Bglane, 64, 131072, Bs + 3 * HSZ, wv);   // B1(1)
    asm volatile("s_waitcnt vmcnt(8)" ::: "memory");   // tile0 landed
    BARX();

    // Φ0 reads: afP = M0(0), bf01 = B0(0)   (consumed at Φ1 of g=0)
    {
        const unsigned short* A0r = As + wr * HSZ;
#pragma unroll
        for (int mi = 0; mi < 4; ++mi) {
            afP[mi][0] = *(const s8v*)&A0r[(mi * 16 + mrow) * 64 + ks0];
            afP[mi][1] = *(const s8v*)&A0r[(mi * 16 + mrow) * 64 + ks1];
        }
        bf01[0][0] = *(const s8v*)&Bs[(browB + mrow) * 64 + ks0];
        bf01[0][1] = *(const s8v*)&Bs[(browB + mrow) * 64 + ks1];
        bf01[1][0] = *(const s8v*)&Bs[(browB + 16 + mrow) * 64 + ks0];
        bf01[1][1] = *(const s8v*)&Bs[(browB + 16 + mrow) * 64 + ks1];
    }

    for (int g = 0; g < NT; ++g) {
        const int c  = g & 1;
        const int cn = c ^ 1;
        const unsigned short* Ard  = As + (c * 2 + wr) * HSZ;   // this tile A
        const unsigned short* B1rd = Bs + (c * 2 + 1) * HSZ;    // this tile B1
        const unsigned short* An   = As + (cn * 2 + wr) * HSZ;  // next tile A
        const unsigned short* B0n  = Bs + (cn * 2 + 0) * HSZ;   // next tile B0
        const int kt2 = (g + 2 < NT ? g + 2 : NT - 1) * 64;

        // ---- Φ1: read bf23(g) ; MFMA(afP, bf01) -------------------------
        bf23[0][0] = *(const s8v*)&B1rd[(browB + mrow) * 64 + ks0];
        bf23[0][1] = *(const s8v*)&B1rd[(browB + mrow) * 64 + ks1];
        bf23[1][0] = *(const s8v*)&B1rd[(browB + 16 + mrow) * 64 + ks0];
        bf23[1][1] = *(const s8v*)&B1rd[(browB + 16 + mrow) * 64 + ks1];
        MFMA_QUAD2(afP, bf01, 0, 0);
        BARX();

        // ---- Φ2: stage B0(g+2)->B[c][0] ; read afQ=M1(g) ; MFMA ---------
        stage2(Bglane, kt2, 0, Bs + (c * 2 + 0) * HSZ, wv);
#pragma unroll
        for (int mi = 0; mi < 4; ++mi) {
            afQ[mi][0] = *(const s8v*)&Ard[(64 + mi * 16 + mrow) * 64 + ks0];
            afQ[mi][1] = *(const s8v*)&Ard[(64 + mi * 16 + mrow) * 64 + ks1];
        }
        MFMA_QUAD2(afP, bf23, 0, 2);
        BARX();

        // ---- Φ3: stage B1(g+2)->B[c][1] ; MFMA(afQ, bf01) ---------------
        stage2(Bglane, kt2, 131072, Bs + (c * 2 + 1) * HSZ, wv);
        MFMA_QUAD2(afQ, bf01, 4, 0);
        BARX();

        // ---- Φ4: vmcnt(4) ; read afP,bf01 (tile g+1, buf cn) ;
        //          stage A0,A1(g+2)->A[c] ; MFMA(afQ, bf23) ---------------
        asm volatile("s_waitcnt vmcnt(4)" ::: "memory");  // tile g+1 landed
#pragma unroll
        for (int mi = 0; mi < 4; ++mi) {
            afP[mi][0] = *(const s8v*)&An[(mi * 16 + mrow) * 64 + ks0];
            afP[mi][1] = *(const s8v*)&An[(mi * 16 + mrow) * 64 + ks1];
        }
        bf01[0][0] = *(const s8v*)&B0n[(browB + mrow) * 64 + ks0];
        bf01[0][1] = *(const s8v*)&B0n[(browB + mrow) * 64 + ks1];
        bf01[1][0] = *(const s8v*)&B0n[(browB + 16 + mrow) * 64 + ks0];
        bf01[1][1] = *(const s8v*)&B0n[(browB + 16 + mrow) * 64 + ks1];
        stage2(Aglane, kt2, 0,      As + (c * 2 + 0) * HSZ, wv);
        stage2(Aglane, kt2, 131072, As + (c * 2 + 1) * HSZ, wv);
        MFMA_QUAD2(afQ, bf23, 4, 2);
        BARX();
    }

    // ----------------------------- epilogue --------------------------------
    const int crow0 = kq * 4;
    const int ccol  = mrow;
    if (MODE == 0) {
        if (tN >= 1024) {
            const int b2  = tM >> 12;
            const int nb0 = (tM & 4095) + wr * 128;
#pragma unroll
            for (int mi = 0; mi < 8; ++mi) {
                const int nbase = nb0 + mi * 16 + crow0;
#pragma unroll
                for (int ni = 0; ni < 4; ++ni) {
                    const int col = tN + (ni >> 1) * 128 + wc * 32 + (ni & 1) * 16 + ccol;
                    f32x4 v = acc[mi][ni];
                    if (col < 2048) {
                        v[0] = fmaxf(v[0], 0.f); v[1] = fmaxf(v[1], 0.f);
                        v[2] = fmaxf(v[2], 0.f); v[3] = fmaxf(v[3], 0.f);
                    }
                    us4 o;
                    o[0] = f2bf(v[0]); o[1] = f2bf(v[1]);
                    o[2] = f2bf(v[2]); o[3] = f2bf(v[3]);
                    *(us4*)&kvT[((size_t)b2 * 2048 + (col - 1024)) * 4096 + nbase] = o;
                }
            }
        } else {
#pragma unroll
            for (int mi = 0; mi < 8; ++mi)
#pragma unroll
                for (int ni = 0; ni < 4; ++ni) {
                    const int row = tM + wr * 128 + mi * 16 + crow0;
                    const int col = tN + (ni >> 1) * 128 + wc * 32 + (ni & 1) * 16 + ccol;
#pragma unroll
                    for (int r2 = 0; r2 < 4; ++r2)
                        Cq[(size_t)(row + r2) * 1024 + col] =
                            f2bf(fmaxf(acc[mi][ni][r2], 0.f));
                }
        }
    } else {
#pragma unroll
        for (int mi = 0; mi < 8; ++mi)
#pragma unroll
            for (int ni = 0; ni < 4; ++ni) {
                const int row = tM + wr * 128 + mi * 16 + crow0;
                const int col = tN + (ni >> 1) * 128 + wc * 32 + (ni & 1) * 16 + ccol;
#pragma unroll
                for (int r2 = 0; r2 < 4; ++r2)
                    Cf[(size_t)(row + r2) * N + col] = acc[mi][ni][r2] + bias[col];
            }
    }
    // drain LDS-DMA before wave exit (LDS may be re-allocated to next block)
    asm volatile("s_waitcnt vmcnt(0)" ::: "memory");
}

// XCD-aware tile map: xcd = blk&7 owns an 8-M-tile stripe; N swept in panels
// of 4 (B-panel 2 MB stays L2-hot), tN fastest within panel.
__device__ __forceinline__ void xcd_map256(int blk, int MT, int& tM, int& tN) {
    const int xcd = blk & 7;
    const int i   = blk >> 3;
    const int MTx = MT >> 3;             // M-tiles per XCD (8)
    const int ppan = MTx * 4;            // blocks per 4-wide panel per XCD
    const int p   = i / ppan;
    const int i2  = i % ppan;
    tM = (xcd * MTx + (i2 >> 2)) * 256;
    tN = (p * 4 + (i2 & 3)) * 256;
}

__global__ __launch_bounds__(512, 2)
void gemm_qkv(const unsigned short* __restrict__ A,
              const unsigned short* __restrict__ Bt,
              unsigned short* __restrict__ Cq, unsigned short* __restrict__ kvT,
              int M, int N) {
    extern __shared__ unsigned short lds[];
    int tM, tN;
    xcd_map256(blockIdx.x, M >> 8, tM, tN);
    gemm_core256<0>(A, Bt, Cq, kvT, nullptr, nullptr, N, tM, tN, lds);
}

__global__ __launch_bounds__(512, 2)
void gemm_proj(const unsigned short* __restrict__ A,
               const unsigned short* __restrict__ Bt,
               float* __restrict__ C, const float* __restrict__ bias,
               int M, int N) {
    extern __shared__ unsigned short lds[];
    int tM, tN;
    xcd_map256(blockIdx.x, M >> 8, tM, tN);
    gemm_core256<1>(A, Bt, nullptr, nullptr, C, bias, N, tM, tN, lds);
}

// ---------------- vk = Vpad @ reluK^T via MFMA over kvT --------------------
__global__ __launch_bounds__(256)
void lite_vk(const unsigned short* __restrict__ kvT, float* __restrict__ vkws) {
    const int bh = blockIdx.x, ck = blockIdx.y;
    const int b = bh >> 5, h = bh & 31;
    const int S = 136;
    __shared__ unsigned short Ks[32 * S];
    __shared__ unsigned short Vs[32 * S];
    __shared__ float Rs[4][1088];
    const int t = threadIdx.x, lane = t & 63, wv = t >> 6;
    const unsigned short* Kp = kvT + ((size_t)b * 2048 + h * 32) * 4096 + ck * 512;
    const unsigned short* Vp = kvT + ((size_t)b * 2048 + 1024 + h * 32) * 4096 + ck * 512;
    const int sr = t >> 3, ss = (t & 7) * 16;
    f32x4 acc00 = {}, acc01 = {}, acc10 = {}, acc11 = {}, accO0 = {}, accO1 = {};
    s8v ones;
#pragma unroll
    for (int j = 0; j < 8; ++j) ones[j] = (short)0x3F80;
    const int mrow = lane & 15, kq = (lane >> 4) * 8;

    for (int tile = 0; tile < 4; ++tile) {
        int go = tile * 128 + ss;
        us8 k0v = *(const us8*)(Kp + (size_t)sr * 4096 + go);
        us8 k1v = *(const us8*)(Kp + (size_t)sr * 4096 + go + 8);
        us8 v0v = *(const us8*)(Vp + (size_t)sr * 4096 + go);
        us8 v1v = *(const us8*)(Vp + (size_t)sr * 4096 + go + 8);
        __syncthreads();
        *(us8*)&Ks[sr * S + ss]     = k0v;
        *(us8*)&Ks[sr * S + ss + 8] = k1v;
        *(us8*)&Vs[sr * S + ss]     = v0v;
        *(us8*)&Vs[sr * S + ss + 8] = v1v;
        __syncthreads();
        int ko = wv * 32 + kq;
        s8v a0 = *(const s8v*)&Vs[(mrow)      * S + ko];
        s8v a1 = *(const s8v*)&Vs[(16 + mrow) * S + ko];
        s8v b0 = *(const s8v*)&Ks[(mrow)      * S + ko];
        s8v b1 = *(const s8v*)&Ks[(16 + mrow) * S + ko];
        acc00 = __builtin_amdgcn_mfma_f32_16x16x32_bf16(a0, b0, acc00, 0, 0, 0);
        acc01 = __builtin_amdgcn_mfma_f32_16x16x32_bf16(a0, b1, acc01, 0, 0, 0);
        acc10 = __builtin_amdgcn_mfma_f32_16x16x32_bf16(a1, b0, acc10, 0, 0, 0);
        acc11 = __builtin_amdgcn_mfma_f32_16x16x32_bf16(a1, b1, acc11, 0, 0, 0);
        accO0 = __builtin_amdgcn_mfma_f32_16x16x32_bf16(ones, b0, accO0, 0, 0, 0);
        accO1 = __builtin_amdgcn_mfma_f32_16x16x32_bf16(ones, b1, accO1, 0, 0, 0);
    }

    const int ccol = lane & 15, crow = (lane >> 4) * 4;
    float* R = Rs[wv];
#pragma unroll
    for (int r2 = 0; r2 < 4; ++r2) {
        R[(crow + r2) * 32 + ccol]           = acc00[r2];
        R[(crow + r2) * 32 + 16 + ccol]      = acc01[r2];
        R[(16 + crow + r2) * 32 + ccol]      = acc10[r2];
        R[(16 + crow + r2) * 32 + 16 + ccol] = acc11[r2];
    }
    if ((lane >> 4) == 0) {
        R[1024 + ccol]      = accO0[0];
        R[1024 + 16 + ccol] = accO1[0];
    }
    __syncthreads();
    float* vkb = vkws + bh * (33 * 32);
    for (int i = t; i < 1056; i += 256) {
        float s = Rs[0][i] + Rs[1][i] + Rs[2][i] + Rs[3][i];
        atomicAdd(&vkb[i], s);
    }
}

// --------------- y = (vk @ reluQ) / pad-row, MFMA K=32 ---------------------
__global__ __launch_bounds__(256)
void lite_apply(const unsigned short* __restrict__ qb,
                const float* __restrict__ vkws,
                unsigned short* __restrict__ yb) {
    const int bh = blockIdx.x, nb = blockIdx.y;
    const int b = bh >> 5, h = bh & 31;
    __shared__ unsigned short vkh[48 * 32];
    __shared__ unsigned short vkl[48 * 32];
    const int t = threadIdx.x;
    for (int i = t; i < 48 * 32; i += 256) {
        float v = (i < 33 * 32) ? vkws[bh * (33 * 32) + i] : 0.f;
        unsigned short hi = f2bf(v);
        vkh[i] = hi;
        vkl[i] = f2bf(v - bf2f(hi));
    }
    __syncthreads();

    const int lane = t & 63, wv = t >> 6;
    const int col = lane & 15, quad = lane >> 4;
    s8v b0h = *(const s8v*)&vkh[(col)      * 32 + quad * 8];
    s8v b0l = *(const s8v*)&vkl[(col)      * 32 + quad * 8];
    s8v b1h = *(const s8v*)&vkh[(16 + col) * 32 + quad * 8];
    s8v b1l = *(const s8v*)&vkl[(16 + col) * 32 + quad * 8];
    s8v b2h = *(const s8v*)&vkh[(32 + col) * 32 + quad * 8];
    s8v b2l = *(const s8v*)&vkl[(32 + col) * 32 + quad * 8];

    const int ntile = nb * 256 + wv * 64;
#pragma unroll
    for (int mi = 0; mi < 4; ++mi) {
        int tok = ntile + mi * 16 + col;
        const unsigned short* qp =
            qb + (size_t)(b * 4096 + tok) * 1024 + h * 32 + quad * 8;
        s8v a = *(const s8v*)qp;
        f32x4 n0 = {}, n1 = {}, dd = {};
        n0 = __builtin_amdgcn_mfma_f32_16x16x32_bf16(b0h, a, n0, 0, 0, 0);
        n0 = __builtin_amdgcn_mfma_f32_16x16x32_bf16(b0l, a, n0, 0, 0, 0);
        n1 = __builtin_amdgcn_mfma_f32_16x16x32_bf16(b1h, a, n1, 0, 0, 0);
        n1 = __builtin_amdgcn_mfma_f32_16x16x32_bf16(b1l, a, n1, 0, 0, 0);
        dd = __builtin_amdgcn_mfma_f32_16x16x32_bf16(b2h, a, dd, 0, 0, 0);
        dd = __builtin_amdgcn_mfma_f32_16x16x32_bf16(b2l, a, dd, 0, 0, 0);
        float den  = __shfl(dd[0], col, 64);
        float rinv = 1.f / (den + 1e-15f);
        us4 o0, o1;
#pragma unroll
        for (int r = 0; r < 4; ++r) {
            o0[r] = f2bf(n0[r] * rinv);
            o1[r] = f2bf(n1[r] * rinv);
        }
        size_t o = (size_t)(b * 4096 + tok) * 1024 + h * 32;
        *(us4*)&yb[o + quad * 4]      = o0;
        *(us4*)&yb[o + 16 + quad * 4] = o1;
    }
}

// ---------------------------------------------------------------------------
extern "C" void kernel_launch(void* const* d_in, const int* in_sizes, int n_in,
                              void* d_out, int out_size, void* d_ws, size_t ws_size,
                              hipStream_t stream) {
    const float* x     = (const float*)d_in[0];   // (4,4096,1024)
    const float* Wqkv  = (const float*)d_in[1];   // (3072,1024)
    const float* Wproj = (const float*)d_in[2];   // (1024,1024)
    const float* bproj = (const float*)d_in[3];   // (1024,)
    float* out = (float*)d_out;                   // (4,4096,1024) fp32

    const int M = 16384, Cdim = 1024, O1 = 3072;

    unsigned short* xb     = (unsigned short*)d_ws;
    unsigned short* wqkvb  = xb + (size_t)M * Cdim;
    unsigned short* wprojb = wqkvb + (size_t)O1 * Cdim;
    unsigned short* qb     = wprojb + (size_t)Cdim * Cdim;        // Q token-major
    unsigned short* kvT    = qb + (size_t)M * Cdim;               // [4][2048][4096]
    unsigned short* ybuf   = kvT + (size_t)4 * 2048 * 4096;
    float* vkws            = (float*)(ybuf + (size_t)M * Cdim);
    // ws use: ~176 MB

    static int attr_done = 0;
    if (!attr_done) {
        hipFuncSetAttribute((const void*)gemm_qkv,
                            hipFuncAttributeMaxDynamicSharedMemorySize, 131072);
        hipFuncSetAttribute((const void*)gemm_proj,
                            hipFuncAttributeMaxDynamicSharedMemorySize, 131072);
        attr_done = 1;
    }

    const int PREP_GROUPS = (16777216 + 3145728 + 1048576 + 135168) / 8;
    prep<<<(PREP_GROUPS + 255) / 256, 256, 0, stream>>>(
        x, Wqkv, Wproj, xb, wqkvb, wprojb, vkws);

    gemm_qkv<<<(M / 256) * (O1 / 256), 512, 131072, stream>>>(
        xb, wqkvb, qb, kvT, M, O1);

    lite_vk<<<dim3(128, 8), 256, 0, stream>>>(kvT, vkws);
    lite_apply<<<dim3(128, 16), 256, 0, stream>>>(qb, vkws, ybuf);

    gemm_proj<<<(M / 256) * (Cdim / 256), 512, 131072, stream>>>(
        ybuf, wprojb, out, bproj, M, Cdim);
}